// Round 14
// baseline (53.302 us; speedup 1.0000x reference)
//
#include <hip/hip_runtime.h>
#include <hip/hip_bf16.h>
#include <math.h>

#define DD 256      // feature dim
#define SS 1024     // seq len
#define BB 8        // batch
#define NN 128      // nodes
#define TOK 16      // tokens per scorer block
#define KC 64       // k-chunk staged in LDS (scorer)
#define NT 8        // nodes per pool tile
#define SC 8        // S-chunks in pool
#define SCH (SS/SC) // 128

// ============ Kernel 1 (r5 verbatim, PASSED @58.6us): fused scorer ============
// h = x @ W1 + b1 ; LN(h) ; GELU(erf) ; score = h @ W2 + b2
// 4 waves/block; wave owns 4 tokens; thread owns 4 columns (c0=4*lane).
// W1 staged in LDS k-chunks of 64 (64 KiB); inner loop pure LDS + FMA.
__global__ __launch_bounds__(256) void scorer_kernel(
    const float* __restrict__ doc, const float* __restrict__ W1,
    const float* __restrict__ b1, const float* __restrict__ gamma,
    const float* __restrict__ beta, const float* __restrict__ W2,
    const float* __restrict__ b2, float* __restrict__ scores)
{
    __shared__ float xs[TOK][DD];    // 16 KiB input tile
    __shared__ float w1s[KC][DD];    // 64 KiB W1 k-chunk

    const int tid  = threadIdx.x;
    const int wave = tid >> 6, lane = tid & 63;
    const int t0   = blockIdx.x * TOK;
    const int c0   = lane * 4;

    {
        const float4* src = reinterpret_cast<const float4*>(doc + (size_t)t0 * DD);
        float4* dst = reinterpret_cast<float4*>(&xs[0][0]);
#pragma unroll
        for (int r = 0; r < 4; ++r) dst[tid + 256 * r] = src[tid + 256 * r];
    }

    float4 acc[4];
    {
        const float4 bv = *reinterpret_cast<const float4*>(b1 + c0);
#pragma unroll
        for (int t = 0; t < 4; ++t) acc[t] = bv;
    }
    const float* xw = &xs[wave * 4][0];

    for (int kc = 0; kc < DD / KC; ++kc) {
        __syncthreads();
        {
            const float4* wsrc = reinterpret_cast<const float4*>(W1 + (size_t)kc * KC * DD);
            float4* wdst = reinterpret_cast<float4*>(&w1s[0][0]);
#pragma unroll
            for (int r = 0; r < 16; ++r) wdst[tid + 256 * r] = wsrc[tid + 256 * r];
        }
        __syncthreads();
#pragma unroll 4
        for (int k4 = 0; k4 < KC / 4; ++k4) {
            const int kb = k4 * 4;
            const float4 w0 = *reinterpret_cast<const float4*>(&w1s[kb + 0][c0]);
            const float4 w1 = *reinterpret_cast<const float4*>(&w1s[kb + 1][c0]);
            const float4 w2 = *reinterpret_cast<const float4*>(&w1s[kb + 2][c0]);
            const float4 w3 = *reinterpret_cast<const float4*>(&w1s[kb + 3][c0]);
#pragma unroll
            for (int t = 0; t < 4; ++t) {
                const float4 xv = *reinterpret_cast<const float4*>(xw + (size_t)t * DD + kc * KC + kb);
                acc[t].x = fmaf(xv.x, w0.x, acc[t].x);
                acc[t].y = fmaf(xv.x, w0.y, acc[t].y);
                acc[t].z = fmaf(xv.x, w0.z, acc[t].z);
                acc[t].w = fmaf(xv.x, w0.w, acc[t].w);
                acc[t].x = fmaf(xv.y, w1.x, acc[t].x);
                acc[t].y = fmaf(xv.y, w1.y, acc[t].y);
                acc[t].z = fmaf(xv.y, w1.z, acc[t].z);
                acc[t].w = fmaf(xv.y, w1.w, acc[t].w);
                acc[t].x = fmaf(xv.z, w2.x, acc[t].x);
                acc[t].y = fmaf(xv.z, w2.y, acc[t].y);
                acc[t].z = fmaf(xv.z, w2.z, acc[t].z);
                acc[t].w = fmaf(xv.z, w2.w, acc[t].w);
                acc[t].x = fmaf(xv.w, w3.x, acc[t].x);
                acc[t].y = fmaf(xv.w, w3.y, acc[t].y);
                acc[t].z = fmaf(xv.w, w3.z, acc[t].z);
                acc[t].w = fmaf(xv.w, w3.w, acc[t].w);
            }
        }
    }

    const float4 gm = *reinterpret_cast<const float4*>(gamma + c0);
    const float4 be = *reinterpret_cast<const float4*>(beta + c0);
    const float4 w2v = *reinterpret_cast<const float4*>(W2 + c0);
    const float b2v = b2[0];

#pragma unroll
    for (int t = 0; t < 4; ++t) {
        float s1 = acc[t].x + acc[t].y + acc[t].z + acc[t].w;
        float s2 = acc[t].x * acc[t].x + acc[t].y * acc[t].y
                 + acc[t].z * acc[t].z + acc[t].w * acc[t].w;
#pragma unroll
        for (int off = 32; off > 0; off >>= 1) {
            s1 += __shfl_xor(s1, off, 64);
            s2 += __shfl_xor(s2, off, 64);
        }
        const float mean = s1 * (1.f / DD);
        const float var  = s2 * (1.f / DD) - mean * mean;
        const float inv  = rsqrtf(var + 1e-5f);
        float n0 = (acc[t].x - mean) * inv * gm.x + be.x;
        float n1 = (acc[t].y - mean) * inv * gm.y + be.y;
        float n2 = (acc[t].z - mean) * inv * gm.z + be.z;
        float n3 = (acc[t].w - mean) * inv * gm.w + be.w;
        const float kq = 0.70710678118654752f;
        float g0 = 0.5f * n0 * (1.f + erff(n0 * kq));
        float g1 = 0.5f * n1 * (1.f + erff(n1 * kq));
        float g2 = 0.5f * n2 * (1.f + erff(n2 * kq));
        float g3 = 0.5f * n3 * (1.f + erff(n3 * kq));
        float sc = g0 * w2v.x + g1 * w2v.y + g2 * w2v.z + g3 * w2v.w;
#pragma unroll
        for (int off = 32; off > 0; off >>= 1) sc += __shfl_xor(sc, off, 64);
        if (lane == 0) scores[t0 + wave * 4 + t] = sc + b2v;
    }
}

// ====== Kernel 2: pool with INLINE softmax-numerator (no stats kernel) ======
// No max-subtraction: |score| is LN-bounded (~<6), exp is safe in f32.
// Per chunk: num[n][d] = sum_s e*doc, zpart[n] = sum_s e  (e = mask ? exp(score) : 0)
// grid = BB*16*SC = 1024; derived from r6's verified pool<8>.
__global__ __launch_bounds__(256) void pool_e_kernel(
    const float* __restrict__ doc, const float* __restrict__ mapping,
    const float* __restrict__ scores, float* __restrict__ part,
    float* __restrict__ zpart)
{
    __shared__ float w_lds[NT][SCH];   // 4 KiB
    __shared__ float z_s[NT];

    const int blk   = blockIdx.x;
    const int c     = blk % SC;
    const int bt    = blk / SC;
    const int ntile = bt & 15;
    const int b     = bt >> 4;
    const int s0    = c * SCH;
    const int tid = threadIdx.x, wave = tid >> 6, lane = tid & 63;

    // phase A: e-weights for NT nodes over this chunk; half-wave per node
    {
        const int nl = wave * 2 + (lane >> 5);
        const int g  = b * NN + ntile * NT + nl;
        const float4 mp = reinterpret_cast<const float4*>(mapping + (size_t)g * SS + s0)[lane & 31];
        const float4 sv = reinterpret_cast<const float4*>(scores + (size_t)b * SS + s0)[lane & 31];
        float4 e;
        e.x = (mp.x > 0.5f) ? __expf(sv.x) : 0.f;
        e.y = (mp.y > 0.5f) ? __expf(sv.y) : 0.f;
        e.z = (mp.z > 0.5f) ? __expf(sv.z) : 0.f;
        e.w = (mp.w > 0.5f) ? __expf(sv.w) : 0.f;
        reinterpret_cast<float4*>(&w_lds[nl][0])[lane & 31] = e;
        float z = e.x + e.y + e.z + e.w;
#pragma unroll
        for (int off = 16; off > 0; off >>= 1) z += __shfl_xor(z, off, 64);  // within 32-lane half
        if ((lane & 31) == 0) z_s[nl] = z;
    }
    __syncthreads();

    // phase C (r6 verbatim structure): acc[n] += w[n][s] * doc[s][tid]
    float acc[NT];
#pragma unroll
    for (int n = 0; n < NT; ++n) acc[n] = 0.f;
    const float* docb = doc + ((size_t)b * SS + s0) * DD;

    float d0 = docb[(size_t)0 * DD + tid], d1 = docb[(size_t)1 * DD + tid];
    float d2 = docb[(size_t)2 * DD + tid], d3 = docb[(size_t)3 * DD + tid];
    for (int s4 = 0; s4 < SCH - 4; s4 += 4) {
        const float n0 = docb[(size_t)(s4 + 4) * DD + tid];
        const float n1 = docb[(size_t)(s4 + 5) * DD + tid];
        const float n2 = docb[(size_t)(s4 + 6) * DD + tid];
        const float n3 = docb[(size_t)(s4 + 7) * DD + tid];
#pragma unroll
        for (int n = 0; n < NT; ++n) {
            const float4 wv = *reinterpret_cast<const float4*>(&w_lds[n][s4]);
            acc[n] = fmaf(wv.x, d0, acc[n]);
            acc[n] = fmaf(wv.y, d1, acc[n]);
            acc[n] = fmaf(wv.z, d2, acc[n]);
            acc[n] = fmaf(wv.w, d3, acc[n]);
        }
        d0 = n0; d1 = n1; d2 = n2; d3 = n3;
    }
    {
        const int s4 = SCH - 4;
#pragma unroll
        for (int n = 0; n < NT; ++n) {
            const float4 wv = *reinterpret_cast<const float4*>(&w_lds[n][s4]);
            acc[n] = fmaf(wv.x, d0, acc[n]);
            acc[n] = fmaf(wv.y, d1, acc[n]);
            acc[n] = fmaf(wv.z, d2, acc[n]);
            acc[n] = fmaf(wv.w, d3, acc[n]);
        }
    }

    float* p = part + (size_t)blk * (NT * DD);
#pragma unroll
    for (int n = 0; n < NT; ++n) p[(size_t)n * DD + tid] = acc[n];
    if (tid < NT) zpart[(size_t)blk * NT + tid] = z_s[tid];
}

// ---------------- Kernel 3: reduce SC chunk-partials + divide by Z ----------------
__global__ __launch_bounds__(256) void reduce_div_kernel(
    const float* __restrict__ part, const float* __restrict__ zpart,
    float* __restrict__ out)
{
    const int o = blockIdx.x * 256 + threadIdx.x;   // B*N*D
    const int d = o & 255;
    const int g = o >> 8;          // b*128 + n
    const int b = g >> 7;
    const int n = g & 127;
    const int ntile = n >> 3, nl = n & 7;
    const int bp0 = (b * 16 + ntile) * SC;
    float s = 0.f, z = 0.f;
#pragma unroll
    for (int c = 0; c < SC; ++c) {
        const int bp = bp0 + c;
        s += part[(size_t)bp * (NT * DD) + (size_t)nl * DD + d];
        z += zpart[(size_t)bp * NT + nl];
    }
    out[o] = (z > 0.f) ? (s / z) : 0.f;
}

// ================= Fallback path (tiny ws): r5 verified kernels =================
__global__ __launch_bounds__(256) void stats_kernel(
    const float* __restrict__ mapping, const float* __restrict__ scores,
    float* __restrict__ mx_out, float* __restrict__ invz_out)
{
    __shared__ float sc_s[SS];
    const int tid = threadIdx.x, wave = tid >> 6, lane = tid & 63;
    const int g0 = blockIdx.x * 4;
    const int b  = g0 >> 7;

    reinterpret_cast<float4*>(sc_s)[tid] =
        reinterpret_cast<const float4*>(scores + (size_t)b * SS)[tid];
    __syncthreads();

    const int g = g0 + wave;
    const float4* mrow4 = reinterpret_cast<const float4*>(mapping + (size_t)g * SS);
    const float4* sc4   = reinterpret_cast<const float4*>(sc_s);

    float4 mv[4], sv[4];
    float mx = -INFINITY;
#pragma unroll
    for (int q = 0; q < 4; ++q) {
        mv[q] = mrow4[lane + (q << 6)];
        sv[q] = sc4[lane + (q << 6)];
        if (mv[q].x > 0.5f) mx = fmaxf(mx, sv[q].x);
        if (mv[q].y > 0.5f) mx = fmaxf(mx, sv[q].y);
        if (mv[q].z > 0.5f) mx = fmaxf(mx, sv[q].z);
        if (mv[q].w > 0.5f) mx = fmaxf(mx, sv[q].w);
    }
#pragma unroll
    for (int off = 32; off > 0; off >>= 1) mx = fmaxf(mx, __shfl_xor(mx, off, 64));
    float z = 0.f;
#pragma unroll
    for (int q = 0; q < 4; ++q) {
        if (mv[q].x > 0.5f) z += __expf(sv[q].x - mx);
        if (mv[q].y > 0.5f) z += __expf(sv[q].y - mx);
        if (mv[q].z > 0.5f) z += __expf(sv[q].z - mx);
        if (mv[q].w > 0.5f) z += __expf(sv[q].w - mx);
    }
#pragma unroll
    for (int off = 32; off > 0; off >>= 1) z += __shfl_xor(z, off, 64);
    if (lane == 0) {
        mx_out[g]   = mx;
        invz_out[g] = (z > 0.f) ? (1.f / z) : 0.f;
    }
}

__global__ __launch_bounds__(256) void pool_direct_kernel(
    const float* __restrict__ doc, const float* __restrict__ mapping,
    const float* __restrict__ scores, const float* __restrict__ mx_in,
    const float* __restrict__ invz_in, float* __restrict__ out)
{
    __shared__ float w_lds[8][SS];

    const int bt    = blockIdx.x;
    const int ntile = bt & 15;
    const int b     = bt >> 4;
    const int tid = threadIdx.x, wave = tid >> 6, lane = tid & 63;

    {
        const int nl = wave * 2 + (lane >> 5);
        const int g  = b * NN + ntile * 8 + nl;
        const float mx   = mx_in[g];
        const float invz = invz_in[g];
        const float4* mrow4 = reinterpret_cast<const float4*>(mapping + (size_t)g * SS);
        const float4* srow4 = reinterpret_cast<const float4*>(scores + (size_t)b * SS);
        float4* wrow4 = reinterpret_cast<float4*>(&w_lds[nl][0]);
        const int idx0 = lane & 31;
#pragma unroll
        for (int q = 0; q < SS / 128; ++q) {
            const int idx = idx0 + 32 * q;
            const float4 mp = mrow4[idx];
            const float4 sv = srow4[idx];
            float4 e;
            e.x = (mp.x > 0.5f) ? __expf(sv.x - mx) * invz : 0.f;
            e.y = (mp.y > 0.5f) ? __expf(sv.y - mx) * invz : 0.f;
            e.z = (mp.z > 0.5f) ? __expf(sv.z - mx) * invz : 0.f;
            e.w = (mp.w > 0.5f) ? __expf(sv.w - mx) * invz : 0.f;
            wrow4[idx] = e;
        }
    }
    __syncthreads();

    float acc[8];
#pragma unroll
    for (int n = 0; n < 8; ++n) acc[n] = 0.f;
    const float* docb = doc + (size_t)b * SS * DD;

    for (int s4 = 0; s4 < SS; s4 += 4) {
        const float d0 = docb[(size_t)(s4 + 0) * DD + tid];
        const float d1 = docb[(size_t)(s4 + 1) * DD + tid];
        const float d2 = docb[(size_t)(s4 + 2) * DD + tid];
        const float d3 = docb[(size_t)(s4 + 3) * DD + tid];
#pragma unroll
        for (int n = 0; n < 8; ++n) {
            const float4 wv = *reinterpret_cast<const float4*>(&w_lds[n][s4]);
            acc[n] = fmaf(wv.x, d0, acc[n]);
            acc[n] = fmaf(wv.y, d1, acc[n]);
            acc[n] = fmaf(wv.z, d2, acc[n]);
            acc[n] = fmaf(wv.w, d3, acc[n]);
        }
    }

    float* outb = out + (((size_t)b * NN) + (size_t)ntile * 8) * DD;
#pragma unroll
    for (int n = 0; n < 8; ++n) outb[(size_t)n * DD + tid] = acc[n];
}

extern "C" void kernel_launch(void* const* d_in, const int* in_sizes, int n_in,
                              void* d_out, int out_size, void* d_ws, size_t ws_size,
                              hipStream_t stream) {
    const float* doc     = (const float*)d_in[0];  // (B,S,D)
    const float* mapping = (const float*)d_in[1];  // (B,N,S)
    // d_in[2] = nodes_len (unused)
    const float* W1    = (const float*)d_in[3];    // (D,D)
    const float* b1    = (const float*)d_in[4];    // (D)
    const float* gamma = (const float*)d_in[5];    // (D)
    const float* beta  = (const float*)d_in[6];    // (D)
    const float* W2    = (const float*)d_in[7];    // (D,1)
    const float* b2    = (const float*)d_in[8];    // (1)
    float* out = (float*)d_out;                    // (B,N,D)

    char* base = (char*)d_ws;
    size_t off = 0;
    float* scores = (float*)(base + off); off += (size_t)BB * SS * 4;                  // 32 KiB
    float* part   = (float*)(base + off); off += (size_t)BB * 16 * SC * NT * DD * 4;   // 8 MiB
    float* zpart  = (float*)(base + off); off += (size_t)BB * 16 * SC * NT * 4;        // 32 KiB
    const size_t need = off;

    scorer_kernel<<<BB * SS / TOK, 256, 0, stream>>>(doc, W1, b1, gamma, beta, W2, b2, scores);

    if (ws_size >= need) {
        pool_e_kernel<<<BB * 16 * SC, 256, 0, stream>>>(doc, mapping, scores, part, zpart);
        reduce_div_kernel<<<(BB * NN * DD) / 256, 256, 0, stream>>>(part, zpart, out);
    } else {
        float* mx   = scores + BB * SS;
        float* invz = mx + BB * NN;
        stats_kernel<<<(BB * NN) / 4, 256, 0, stream>>>(mapping, scores, mx, invz);
        pool_direct_kernel<<<BB * 16, 256, 0, stream>>>(doc, mapping, scores, mx, invz, out);
    }
}

// Round 15
// 53.085 us; speedup vs baseline: 1.0041x; 1.0041x over previous
//
#include <hip/hip_runtime.h>
#include <hip/hip_bf16.h>
#include <math.h>

#define DD 256      // feature dim
#define SS 1024     // seq len
#define BB 8        // batch
#define NN 128      // nodes
#define TOK 16      // tokens per scorer block
#define KC 64       // k-chunk staged in LDS (scorer)
#define NT 8        // nodes per pool tile
#define SC 8        // S-chunks in pool
#define SCH (SS/SC) // 128

// ============ Kernel 1 (r5 verbatim, PASSED @58.6us): fused scorer ============
// h = x @ W1 + b1 ; LN(h) ; GELU(erf) ; score = h @ W2 + b2
// 4 waves/block; wave owns 4 tokens; thread owns 4 columns (c0=4*lane).
// W1 staged in LDS k-chunks of 64 (64 KiB); inner loop pure LDS + FMA.
__global__ __launch_bounds__(256) void scorer_kernel(
    const float* __restrict__ doc, const float* __restrict__ W1,
    const float* __restrict__ b1, const float* __restrict__ gamma,
    const float* __restrict__ beta, const float* __restrict__ W2,
    const float* __restrict__ b2, float* __restrict__ scores)
{
    __shared__ float xs[TOK][DD];    // 16 KiB input tile
    __shared__ float w1s[KC][DD];    // 64 KiB W1 k-chunk

    const int tid  = threadIdx.x;
    const int wave = tid >> 6, lane = tid & 63;
    const int t0   = blockIdx.x * TOK;
    const int c0   = lane * 4;

    {
        const float4* src = reinterpret_cast<const float4*>(doc + (size_t)t0 * DD);
        float4* dst = reinterpret_cast<float4*>(&xs[0][0]);
#pragma unroll
        for (int r = 0; r < 4; ++r) dst[tid + 256 * r] = src[tid + 256 * r];
    }

    float4 acc[4];
    {
        const float4 bv = *reinterpret_cast<const float4*>(b1 + c0);
#pragma unroll
        for (int t = 0; t < 4; ++t) acc[t] = bv;
    }
    const float* xw = &xs[wave * 4][0];

    for (int kc = 0; kc < DD / KC; ++kc) {
        __syncthreads();
        {
            const float4* wsrc = reinterpret_cast<const float4*>(W1 + (size_t)kc * KC * DD);
            float4* wdst = reinterpret_cast<float4*>(&w1s[0][0]);
#pragma unroll
            for (int r = 0; r < 16; ++r) wdst[tid + 256 * r] = wsrc[tid + 256 * r];
        }
        __syncthreads();
#pragma unroll 4
        for (int k4 = 0; k4 < KC / 4; ++k4) {
            const int kb = k4 * 4;
            const float4 w0 = *reinterpret_cast<const float4*>(&w1s[kb + 0][c0]);
            const float4 w1 = *reinterpret_cast<const float4*>(&w1s[kb + 1][c0]);
            const float4 w2 = *reinterpret_cast<const float4*>(&w1s[kb + 2][c0]);
            const float4 w3 = *reinterpret_cast<const float4*>(&w1s[kb + 3][c0]);
#pragma unroll
            for (int t = 0; t < 4; ++t) {
                const float4 xv = *reinterpret_cast<const float4*>(xw + (size_t)t * DD + kc * KC + kb);
                acc[t].x = fmaf(xv.x, w0.x, acc[t].x);
                acc[t].y = fmaf(xv.x, w0.y, acc[t].y);
                acc[t].z = fmaf(xv.x, w0.z, acc[t].z);
                acc[t].w = fmaf(xv.x, w0.w, acc[t].w);
                acc[t].x = fmaf(xv.y, w1.x, acc[t].x);
                acc[t].y = fmaf(xv.y, w1.y, acc[t].y);
                acc[t].z = fmaf(xv.y, w1.z, acc[t].z);
                acc[t].w = fmaf(xv.y, w1.w, acc[t].w);
                acc[t].x = fmaf(xv.z, w2.x, acc[t].x);
                acc[t].y = fmaf(xv.z, w2.y, acc[t].y);
                acc[t].z = fmaf(xv.z, w2.z, acc[t].z);
                acc[t].w = fmaf(xv.z, w2.w, acc[t].w);
                acc[t].x = fmaf(xv.w, w3.x, acc[t].x);
                acc[t].y = fmaf(xv.w, w3.y, acc[t].y);
                acc[t].z = fmaf(xv.w, w3.z, acc[t].z);
                acc[t].w = fmaf(xv.w, w3.w, acc[t].w);
            }
        }
    }

    const float4 gm = *reinterpret_cast<const float4*>(gamma + c0);
    const float4 be = *reinterpret_cast<const float4*>(beta + c0);
    const float4 w2v = *reinterpret_cast<const float4*>(W2 + c0);
    const float b2v = b2[0];

#pragma unroll
    for (int t = 0; t < 4; ++t) {
        float s1 = acc[t].x + acc[t].y + acc[t].z + acc[t].w;
        float s2 = acc[t].x * acc[t].x + acc[t].y * acc[t].y
                 + acc[t].z * acc[t].z + acc[t].w * acc[t].w;
#pragma unroll
        for (int off = 32; off > 0; off >>= 1) {
            s1 += __shfl_xor(s1, off, 64);
            s2 += __shfl_xor(s2, off, 64);
        }
        const float mean = s1 * (1.f / DD);
        const float var  = s2 * (1.f / DD) - mean * mean;
        const float inv  = rsqrtf(var + 1e-5f);
        float n0 = (acc[t].x - mean) * inv * gm.x + be.x;
        float n1 = (acc[t].y - mean) * inv * gm.y + be.y;
        float n2 = (acc[t].z - mean) * inv * gm.z + be.z;
        float n3 = (acc[t].w - mean) * inv * gm.w + be.w;
        const float kq = 0.70710678118654752f;
        float g0 = 0.5f * n0 * (1.f + erff(n0 * kq));
        float g1 = 0.5f * n1 * (1.f + erff(n1 * kq));
        float g2 = 0.5f * n2 * (1.f + erff(n2 * kq));
        float g3 = 0.5f * n3 * (1.f + erff(n3 * kq));
        float sc = g0 * w2v.x + g1 * w2v.y + g2 * w2v.z + g3 * w2v.w;
#pragma unroll
        for (int off = 32; off > 0; off >>= 1) sc += __shfl_xor(sc, off, 64);
        if (lane == 0) scores[t0 + wave * 4 + t] = sc + b2v;
    }
}

// ====== Kernel 2: pool with INLINE softmax-numerator (no stats kernel) ======
// No max-subtraction: |score| is LN-bounded (~<6), exp is safe in f32.
// Per chunk: num[n][d] = sum_s e*doc, zpart[n] = sum_s e  (e = mask ? exp(score) : 0)
// grid = BB*16*SC = 1024; derived from r6's verified pool<8>.
__global__ __launch_bounds__(256) void pool_e_kernel(
    const float* __restrict__ doc, const float* __restrict__ mapping,
    const float* __restrict__ scores, float* __restrict__ part,
    float* __restrict__ zpart)
{
    __shared__ float w_lds[NT][SCH];   // 4 KiB
    __shared__ float z_s[NT];

    const int blk   = blockIdx.x;
    const int c     = blk % SC;
    const int bt    = blk / SC;
    const int ntile = bt & 15;
    const int b     = bt >> 4;
    const int s0    = c * SCH;
    const int tid = threadIdx.x, wave = tid >> 6, lane = tid & 63;

    // phase A: e-weights for NT nodes over this chunk; half-wave per node
    {
        const int nl = wave * 2 + (lane >> 5);
        const int g  = b * NN + ntile * NT + nl;
        const float4 mp = reinterpret_cast<const float4*>(mapping + (size_t)g * SS + s0)[lane & 31];
        const float4 sv = reinterpret_cast<const float4*>(scores + (size_t)b * SS + s0)[lane & 31];
        float4 e;
        e.x = (mp.x > 0.5f) ? __expf(sv.x) : 0.f;
        e.y = (mp.y > 0.5f) ? __expf(sv.y) : 0.f;
        e.z = (mp.z > 0.5f) ? __expf(sv.z) : 0.f;
        e.w = (mp.w > 0.5f) ? __expf(sv.w) : 0.f;
        reinterpret_cast<float4*>(&w_lds[nl][0])[lane & 31] = e;
        float z = e.x + e.y + e.z + e.w;
#pragma unroll
        for (int off = 16; off > 0; off >>= 1) z += __shfl_xor(z, off, 64);  // within 32-lane half
        if ((lane & 31) == 0) z_s[nl] = z;
    }
    __syncthreads();

    // phase C (r6 verbatim structure): acc[n] += w[n][s] * doc[s][tid]
    float acc[NT];
#pragma unroll
    for (int n = 0; n < NT; ++n) acc[n] = 0.f;
    const float* docb = doc + ((size_t)b * SS + s0) * DD;

    float d0 = docb[(size_t)0 * DD + tid], d1 = docb[(size_t)1 * DD + tid];
    float d2 = docb[(size_t)2 * DD + tid], d3 = docb[(size_t)3 * DD + tid];
    for (int s4 = 0; s4 < SCH - 4; s4 += 4) {
        const float n0 = docb[(size_t)(s4 + 4) * DD + tid];
        const float n1 = docb[(size_t)(s4 + 5) * DD + tid];
        const float n2 = docb[(size_t)(s4 + 6) * DD + tid];
        const float n3 = docb[(size_t)(s4 + 7) * DD + tid];
#pragma unroll
        for (int n = 0; n < NT; ++n) {
            const float4 wv = *reinterpret_cast<const float4*>(&w_lds[n][s4]);
            acc[n] = fmaf(wv.x, d0, acc[n]);
            acc[n] = fmaf(wv.y, d1, acc[n]);
            acc[n] = fmaf(wv.z, d2, acc[n]);
            acc[n] = fmaf(wv.w, d3, acc[n]);
        }
        d0 = n0; d1 = n1; d2 = n2; d3 = n3;
    }
    {
        const int s4 = SCH - 4;
#pragma unroll
        for (int n = 0; n < NT; ++n) {
            const float4 wv = *reinterpret_cast<const float4*>(&w_lds[n][s4]);
            acc[n] = fmaf(wv.x, d0, acc[n]);
            acc[n] = fmaf(wv.y, d1, acc[n]);
            acc[n] = fmaf(wv.z, d2, acc[n]);
            acc[n] = fmaf(wv.w, d3, acc[n]);
        }
    }

    float* p = part + (size_t)blk * (NT * DD);
#pragma unroll
    for (int n = 0; n < NT; ++n) p[(size_t)n * DD + tid] = acc[n];
    if (tid < NT) zpart[(size_t)blk * NT + tid] = z_s[tid];
}

// ---------------- Kernel 3: reduce SC chunk-partials + divide by Z ----------------
__global__ __launch_bounds__(256) void reduce_div_kernel(
    const float* __restrict__ part, const float* __restrict__ zpart,
    float* __restrict__ out)
{
    const int o = blockIdx.x * 256 + threadIdx.x;   // B*N*D
    const int d = o & 255;
    const int g = o >> 8;          // b*128 + n
    const int b = g >> 7;
    const int n = g & 127;
    const int ntile = n >> 3, nl = n & 7;
    const int bp0 = (b * 16 + ntile) * SC;
    float s = 0.f, z = 0.f;
#pragma unroll
    for (int c = 0; c < SC; ++c) {
        const int bp = bp0 + c;
        s += part[(size_t)bp * (NT * DD) + (size_t)nl * DD + d];
        z += zpart[(size_t)bp * NT + nl];
    }
    out[o] = (z > 0.f) ? (s / z) : 0.f;
}

// ================= Fallback path (tiny ws): r5 verified kernels =================
__global__ __launch_bounds__(256) void stats_kernel(
    const float* __restrict__ mapping, const float* __restrict__ scores,
    float* __restrict__ mx_out, float* __restrict__ invz_out)
{
    __shared__ float sc_s[SS];
    const int tid = threadIdx.x, wave = tid >> 6, lane = tid & 63;
    const int g0 = blockIdx.x * 4;
    const int b  = g0 >> 7;

    reinterpret_cast<float4*>(sc_s)[tid] =
        reinterpret_cast<const float4*>(scores + (size_t)b * SS)[tid];
    __syncthreads();

    const int g = g0 + wave;
    const float4* mrow4 = reinterpret_cast<const float4*>(mapping + (size_t)g * SS);
    const float4* sc4   = reinterpret_cast<const float4*>(sc_s);

    float4 mv[4], sv[4];
    float mx = -INFINITY;
#pragma unroll
    for (int q = 0; q < 4; ++q) {
        mv[q] = mrow4[lane + (q << 6)];
        sv[q] = sc4[lane + (q << 6)];
        if (mv[q].x > 0.5f) mx = fmaxf(mx, sv[q].x);
        if (mv[q].y > 0.5f) mx = fmaxf(mx, sv[q].y);
        if (mv[q].z > 0.5f) mx = fmaxf(mx, sv[q].z);
        if (mv[q].w > 0.5f) mx = fmaxf(mx, sv[q].w);
    }
#pragma unroll
    for (int off = 32; off > 0; off >>= 1) mx = fmaxf(mx, __shfl_xor(mx, off, 64));
    float z = 0.f;
#pragma unroll
    for (int q = 0; q < 4; ++q) {
        if (mv[q].x > 0.5f) z += __expf(sv[q].x - mx);
        if (mv[q].y > 0.5f) z += __expf(sv[q].y - mx);
        if (mv[q].z > 0.5f) z += __expf(sv[q].z - mx);
        if (mv[q].w > 0.5f) z += __expf(sv[q].w - mx);
    }
#pragma unroll
    for (int off = 32; off > 0; off >>= 1) z += __shfl_xor(z, off, 64);
    if (lane == 0) {
        mx_out[g]   = mx;
        invz_out[g] = (z > 0.f) ? (1.f / z) : 0.f;
    }
}

__global__ __launch_bounds__(256) void pool_direct_kernel(
    const float* __restrict__ doc, const float* __restrict__ mapping,
    const float* __restrict__ scores, const float* __restrict__ mx_in,
    const float* __restrict__ invz_in, float* __restrict__ out)
{
    __shared__ float w_lds[8][SS];

    const int bt    = blockIdx.x;
    const int ntile = bt & 15;
    const int b     = bt >> 4;
    const int tid = threadIdx.x, wave = tid >> 6, lane = tid & 63;

    {
        const int nl = wave * 2 + (lane >> 5);
        const int g  = b * NN + ntile * 8 + nl;
        const float mx   = mx_in[g];
        const float invz = invz_in[g];
        const float4* mrow4 = reinterpret_cast<const float4*>(mapping + (size_t)g * SS);
        const float4* srow4 = reinterpret_cast<const float4*>(scores + (size_t)b * SS);
        float4* wrow4 = reinterpret_cast<float4*>(&w_lds[nl][0]);
        const int idx0 = lane & 31;
#pragma unroll
        for (int q = 0; q < SS / 128; ++q) {
            const int idx = idx0 + 32 * q;
            const float4 mp = mrow4[idx];
            const float4 sv = srow4[idx];
            float4 e;
            e.x = (mp.x > 0.5f) ? __expf(sv.x - mx) * invz : 0.f;
            e.y = (mp.y > 0.5f) ? __expf(sv.y - mx) * invz : 0.f;
            e.z = (mp.z > 0.5f) ? __expf(sv.z - mx) * invz : 0.f;
            e.w = (mp.w > 0.5f) ? __expf(sv.w - mx) * invz : 0.f;
            wrow4[idx] = e;
        }
    }
    __syncthreads();

    float acc[8];
#pragma unroll
    for (int n = 0; n < 8; ++n) acc[n] = 0.f;
    const float* docb = doc + (size_t)b * SS * DD;

    for (int s4 = 0; s4 < SS; s4 += 4) {
        const float d0 = docb[(size_t)(s4 + 0) * DD + tid];
        const float d1 = docb[(size_t)(s4 + 1) * DD + tid];
        const float d2 = docb[(size_t)(s4 + 2) * DD + tid];
        const float d3 = docb[(size_t)(s4 + 3) * DD + tid];
#pragma unroll
        for (int n = 0; n < 8; ++n) {
            const float4 wv = *reinterpret_cast<const float4*>(&w_lds[n][s4]);
            acc[n] = fmaf(wv.x, d0, acc[n]);
            acc[n] = fmaf(wv.y, d1, acc[n]);
            acc[n] = fmaf(wv.z, d2, acc[n]);
            acc[n] = fmaf(wv.w, d3, acc[n]);
        }
    }

    float* outb = out + (((size_t)b * NN) + (size_t)ntile * 8) * DD;
#pragma unroll
    for (int n = 0; n < 8; ++n) outb[(size_t)n * DD + tid] = acc[n];
}

extern "C" void kernel_launch(void* const* d_in, const int* in_sizes, int n_in,
                              void* d_out, int out_size, void* d_ws, size_t ws_size,
                              hipStream_t stream) {
    const float* doc     = (const float*)d_in[0];  // (B,S,D)
    const float* mapping = (const float*)d_in[1];  // (B,N,S)
    // d_in[2] = nodes_len (unused)
    const float* W1    = (const float*)d_in[3];    // (D,D)
    const float* b1    = (const float*)d_in[4];    // (D)
    const float* gamma = (const float*)d_in[5];    // (D)
    const float* beta  = (const float*)d_in[6];    // (D)
    const float* W2    = (const float*)d_in[7];    // (D,1)
    const float* b2    = (const float*)d_in[8];    // (1)
    float* out = (float*)d_out;                    // (B,N,D)

    char* base = (char*)d_ws;
    size_t off = 0;
    float* scores = (float*)(base + off); off += (size_t)BB * SS * 4;                  // 32 KiB
    float* part   = (float*)(base + off); off += (size_t)BB * 16 * SC * NT * DD * 4;   // 8 MiB
    float* zpart  = (float*)(base + off); off += (size_t)BB * 16 * SC * NT * 4;        // 32 KiB
    const size_t need = off;

    scorer_kernel<<<BB * SS / TOK, 256, 0, stream>>>(doc, W1, b1, gamma, beta, W2, b2, scores);

    if (ws_size >= need) {
        pool_e_kernel<<<BB * 16 * SC, 256, 0, stream>>>(doc, mapping, scores, part, zpart);
        reduce_div_kernel<<<(BB * NN * DD) / 256, 256, 0, stream>>>(part, zpart, out);
    } else {
        float* mx   = scores + BB * SS;
        float* invz = mx + BB * NN;
        stats_kernel<<<(BB * NN) / 4, 256, 0, stream>>>(mapping, scores, mx, invz);
        pool_direct_kernel<<<BB * 16, 256, 0, stream>>>(doc, mapping, scores, mx, invz, out);
    }
}